// Round 4
// baseline (137.159 us; speedup 1.0000x reference)
//
#include <hip/hip_runtime.h>

// KAN layer as one fused fp16 MFMA GEMM:
//   out[b,i] = sum_j [ neg*bw*pw + pos*bw + sum_k basis[b,j,k]*sw[i,j]*sc[i,j,k] ]
// A  [2048 x 11264] fp16 : per j, 22 slots = {20 basis (5 nonzero), neg, pos}
// Ct [ 512 x 11264] fp16 : per j, 22 slots = {sw*sc[0..19], bw*pw, bw}   (B^T layout)
// R8: two fixes from the R7 post-mortem (gemm is LDS-pipe-bound, not
//     schedule-bound; prep is instruction-churn-bound, not memory-bound):
//  (a) gemm: 256x256 tile (wave-tile 128x64, 2x4 waves) — 40% less LDS
//      fragment traffic per FLOP; KSPLIT=16 keeps 256 blocks = 1/CU; 2-buffer
//      dbuf (128 KB), 4 fat phases/K-step (16 MFMA per barrier-pair, half of
//      R7's barrier rate), stage issued one full K-step ahead, loop-top
//      vmcnt(8) (never 0 until last tile). reduce16 eats +5 us (71 MB).
//  (b) prep: 4-record (176 B, 16B-aligned) granularity. prep_C fully in
//      registers (no LDS/barrier, 11 dwordx4 stores per thread). prep_A:
//      private-LDS scatter (stride-176 = 11 quads, odd -> conflict-free
//      b128), one barrier, coalesced 2-row cooperative store.
// ws usage: A = 46.1 MB, Ct = 11.5 MB, partials16 = 67.1 MB (124.9 MB total).

typedef _Float16 half_t;
typedef __attribute__((ext_vector_type(8))) _Float16 half8;
typedef __attribute__((ext_vector_type(4))) float floatx4;

#define B_DIM   2048
#define J_DIM   512
#define O_DIM   512
#define SLOTS   22
#define K_TOT   (J_DIM * SLOTS)      // 11264
#define BM      256
#define BN      256
#define BK      64
#define KSPLIT  16                   // 2 z per XCD

// ---------------------------------------------------------------------------
// Quartic B-spline local basis, uniform knots g_i = -1.5 + i*(3.125/24).
// (Reference quirk: linspace(-1.5, 1.625, 25) -> spacing 3.125/24, NOT 0.125.)
// m in [3,19]; window k = m-4 .. m, entries with k<0 dropped.
__device__ __forceinline__ void bspline5(float xc, int& k0, float Nv[5]) {
    const float invS = 7.68f;              // 24/3.125 (exact ratio)
    float u = (xc + 1.5f) * invS;          // knot units
    int m = (int)u;
    m = min(max(m, 3), 19);
    k0 = m - 4;
    Nv[0] = 1.f; Nv[1] = 0.f; Nv[2] = 0.f; Nv[3] = 0.f; Nv[4] = 0.f;
#pragma unroll
    for (int d = 1; d <= 4; ++d) {
        float nw[5];
        float inv_d = 1.0f / (float)d;
#pragma unroll
        for (int r = 0; r < 5; ++r) {
            if (r > d) { nw[r] = 0.f; continue; }
            float kk = (float)(m - d + r);
            float acc = 0.f;
            if (r >= 1) acc += (u - kk) * Nv[r - 1];
            if (r < d)  acc += (kk + (float)(d + 1) - u) * Nv[r];
            nw[r] = acc * inv_d;
        }
#pragma unroll
        for (int r = 0; r < 5; ++r) Nv[r] = nw[r];
    }
}

__device__ __forceinline__ unsigned packh2(float a, float b) {
    half_t ha = (half_t)a, hb = (half_t)b;    // RTN, identical to old path
    unsigned short ua = __builtin_bit_cast(unsigned short, ha);
    unsigned short ub = __builtin_bit_cast(unsigned short, hb);
    return (unsigned)ua | ((unsigned)ub << 16);
}

// ---------------------------------------------------------------------------
// prep2: blocks [0,256) build Ct (2 i-rows each, register-only);
//        blocks [256,1280) build A (2 b-rows each, private-LDS scatter).
// Thread: sub = t>>7 selects the row within the block; jq = t&127 -> j0=4*jq.
__global__ __launch_bounds__(256) void prep2(const float* __restrict__ x,
                                             const float* __restrict__ pw,
                                             const float* __restrict__ bw,
                                             const float* __restrict__ sw,
                                             const float* __restrict__ sc,
                                             half_t* __restrict__ A,
                                             half_t* __restrict__ Ct) {
    __shared__ half_t sbuf[2][128 * 88];   // 45056 B, prep_A path only
    int bid = blockIdx.x;
    int t = threadIdx.x;
    int sub = t >> 7;          // 0/1: which row of the block's pair
    int jq  = t & 127;         // j-quad index
    int j0  = jq * 4;

    if (bid < 256) {
        // ---- prep_C: 4 records built fully in registers, no LDS.
        int i = bid * 2 + sub;
        size_t ij0 = (size_t)i * J_DIM + j0;
        float4 s4 = *(const float4*)(sw + ij0);
        float4 b4 = *(const float4*)(bw + ij0);
        float4 p4 = *(const float4*)(pw + ij0);
        const float4* sp4 = (const float4*)(sc + ij0 * 20);  // 20 float4s
        unsigned u[44];
#pragma unroll
        for (int jj = 0; jj < 4; ++jj) {
            float s = ((const float*)&s4)[jj];
            float b = ((const float*)&b4)[jj];
            float p = ((const float*)&p4)[jj];
#pragma unroll
            for (int v = 0; v < 5; ++v) {                   // 20 coeffs
                float4 c4 = sp4[jj * 5 + v];
                u[jj * 11 + v * 2 + 0] = packh2(s * c4.x, s * c4.y);
                u[jj * 11 + v * 2 + 1] = packh2(s * c4.z, s * c4.w);
            }
            u[jj * 11 + 10] = packh2(b * p, b);             // slots 20,21
        }
        uint4* dst = (uint4*)(Ct + (size_t)i * K_TOT + (size_t)j0 * SLOTS);
#pragma unroll
        for (int v = 0; v < 11; ++v)
            dst[v] = make_uint4(u[4 * v], u[4 * v + 1], u[4 * v + 2], u[4 * v + 3]);
        return;
    }

    // ---- prep_A: 4 records via private-LDS scatter (no cross-thread deps
    // until the single pre-copy barrier).
    int b0 = (bid - 256) * 2;
    int b = b0 + sub;
    float4 x4 = *(const float4*)(x + (size_t)b * J_DIM + j0);
    half_t* reg = &sbuf[sub][jq * 88];      // 176 B, 16B-aligned, stride 11 quads

    // zero 88 halfs with 11 conflict-free b128 writes (stride 176 B = 11 quads)
    half8 z;
#pragma unroll
    for (int e = 0; e < 8; ++e) z[e] = (half_t)0.f;
#pragma unroll
    for (int v = 0; v < 11; ++v) *(half8*)(reg + v * 8) = z;

#pragma unroll
    for (int jj = 0; jj < 4; ++jj) {
        float xv = ((const float*)&x4)[jj];
        float xc = fminf(fmaxf(xv, -1.f), 1.f);
        float pos = fmaxf(xc, 0.f);
        float neg = xc - pos;
        int k0; float Nv[5];
        bspline5(xc, k0, Nv);
        half_t* rb = reg + jj * SLOTS;
#pragma unroll
        for (int rr = 0; rr < 5; ++rr) {
            int k = k0 + rr;
            if (k >= 0) rb[k] = (half_t)Nv[rr];   // k <= 19 guaranteed
        }
        *(unsigned*)(rb + 20) = packh2(neg, pos); // 4B-aligned (44*jj+40)
    }
    __syncthreads();

    // coalesced cooperative store of the 2 complete rows (45056 B)
    const uint4* src = (const uint4*)&sbuf[0][0];
    uint4* dst = (uint4*)(A + (size_t)b0 * K_TOT);
#pragma unroll
    for (int v = 0; v < 11; ++v) dst[v * 256 + t] = src[v * 256 + t];
}

// ---------------------------------------------------------------------------
// gemm16: grid (8,2,16) = 256 blocks (1/CU), 512 thr = 8 waves (2m x 4n),
// wave-tile 128x64, acc[8][4]. 2-buffer dbuf; tile T+2 issued at the END of
// tile T's phases (a full K-step of issue->wait distance, > HBM latency);
// loop top waits vmcnt(8) (T done, T+1's 8 still flying). 4 phases/K-step:
//   { ds_read 4 af (ph0: +8 bf) ; barrier ; setprio(1) 16 MFMA setprio(0) ;
//     barrier }
// XOR-quad swizzle both-sides (pre-swizzled global source for the linear
// global_load_lds dest; XOR'd ds_read offset) — <=2-way banks.
// XCD pin: lid%8 = XCD c gets bz in {c, c+8} (A-slice 5.77 MB + Ct 1.44 MB).
__global__ __launch_bounds__(512, 2) void gemm16_f16(const half_t* __restrict__ A,
                                                     const half_t* __restrict__ Bt,
                                                     float* __restrict__ out) {
    constexpr int KS_LEN = K_TOT / KSPLIT;     // 704
    constexpr int NSTEP = KS_LEN / BK;         // 11

    __shared__ half_t As[2][BM * BK];   // 2 x 32 KB
    __shared__ half_t Bs[2][BN * BK];   // 2 x 32 KB  -> 128 KB total

    int lid = blockIdx.x + 8 * (blockIdx.y + 2 * blockIdx.z);   // 0..255
    int c = lid & 7;                 // XCD
    int r = lid >> 3;                // 0..31
    int bz = c + 8 * (r & 1);        // z in {c, c+8}
    int rr = r >> 1;                 // 0..15
    int bx = rr & 7;                 // 8 m-blocks
    int by = rr >> 3;                // 2 n-blocks

    int m0 = bx * BM, n0 = by * BN, ks = bz * KS_LEN;

    int t = threadIdx.x;
    int w = t >> 6, l = t & 63;
    int wm = w >> 2, wn = w & 3;          // wave grid 2 x 4
    int q = l >> 4, fr = l & 15;          // MFMA fragment coords

    const half_t* gA = A + (size_t)m0 * K_TOT + ks;
    const half_t* gB = Bt + (size_t)n0 * K_TOT + ks;

    int srow = l >> 3;                    // 0..7
    int sq = ((l & 7) ^ srow) * 8;        // pre-swizzled source quad (halfs)
    int fsw0 = ((q)     ^ (fr & 7)) * 8;  // read-side swizzled k-offsets
    int fsw1 = ((4 + q) ^ (fr & 7)) * 8;

    floatx4 acc[8][4] = {};

// one tile = 8 loads/wave (A s0..3, B s0..3); vmcnt counts in 8s.
#define ISSUE(kb, p)                                                          \
    {                                                                         \
        _Pragma("unroll")                                                     \
        for (int s = 0; s < 4; ++s)                                           \
            __builtin_amdgcn_global_load_lds(                                 \
                (const __attribute__((address_space(1))) unsigned int*)       \
                    (gA + (size_t)(w * 32 + s * 8 + srow) * K_TOT + (kb) + sq),\
                (__attribute__((address_space(3))) unsigned int*)             \
                    (&As[p][(w * 32 + s * 8) * BK]),                          \
                16, 0, 0);                                                    \
        _Pragma("unroll")                                                     \
        for (int s = 0; s < 4; ++s)                                           \
            __builtin_amdgcn_global_load_lds(                                 \
                (const __attribute__((address_space(1))) unsigned int*)       \
                    (gB + (size_t)(w * 32 + s * 8 + srow) * K_TOT + (kb) + sq),\
                (__attribute__((address_space(3))) unsigned int*)             \
                    (&Bs[p][(w * 32 + s * 8) * BK]),                          \
                16, 0, 0);                                                    \
    }

#define AFRD(mt, kss) (*(const half8*)(Ab + ((wm << 7) + ((mt) << 4) + fr) * BK + (kss)))
#define BFRD(nt, kss) (*(const half8*)(Bb + ((wn << 6) + ((nt) << 4) + fr) * BK + (kss)))

// phase p: mt pair {2p, 2p+1} x all 4 nt x 2 ksub = 16 MFMA
#define PHASE(p, EXTRA)                                                       \
    {                                                                         \
        half8 a0 = AFRD(2 * (p), fsw0), a1 = AFRD(2 * (p), fsw1);             \
        half8 a2 = AFRD(2 * (p) + 1, fsw0), a3 = AFRD(2 * (p) + 1, fsw1);     \
        EXTRA                                                                 \
        __builtin_amdgcn_s_barrier();                                         \
        __builtin_amdgcn_s_setprio(1);                                        \
        _Pragma("unroll")                                                     \
        for (int nt = 0; nt < 4; ++nt) {                                      \
            acc[2 * (p)][nt] = __builtin_amdgcn_mfma_f32_16x16x32_f16(        \
                a0, bfr[nt][0], acc[2 * (p)][nt], 0, 0, 0);                   \
            acc[2 * (p)][nt] = __builtin_amdgcn_mfma_f32_16x16x32_f16(        \
                a1, bfr[nt][1], acc[2 * (p)][nt], 0, 0, 0);                   \
            acc[2 * (p) + 1][nt] = __builtin_amdgcn_mfma_f32_16x16x32_f16(    \
                a2, bfr[nt][0], acc[2 * (p) + 1][nt], 0, 0, 0);               \
            acc[2 * (p) + 1][nt] = __builtin_amdgcn_mfma_f32_16x16x32_f16(    \
                a3, bfr[nt][1], acc[2 * (p) + 1][nt], 0, 0, 0);               \
        }                                                                     \
        __builtin_amdgcn_s_setprio(0);                                        \
        __builtin_amdgcn_s_barrier();                                         \
    }

    ISSUE(0, 0)
    ISSUE(BK, 1)

    for (int T = 0; T < NSTEP; ++T) {
        if (T < NSTEP - 1) { asm volatile("s_waitcnt vmcnt(8)" ::: "memory"); }
        else               { asm volatile("s_waitcnt vmcnt(0)" ::: "memory"); }
        __builtin_amdgcn_s_barrier();

        const half_t* Ab = &As[T & 1][0];
        const half_t* Bb = &Bs[T & 1][0];
        half8 bfr[4][2];

        PHASE(0,
            _Pragma("unroll")
            for (int nt = 0; nt < 4; ++nt) {
                bfr[nt][0] = BFRD(nt, fsw0);
                bfr[nt][1] = BFRD(nt, fsw1);
            }
        )
        PHASE(1, )
        PHASE(2, )
        PHASE(3, )

        // stage T+2 into the buffer just fully consumed (safe: post-barrier)
        if (T + 2 < NSTEP) ISSUE((T + 2) * BK, T & 1)
    }
#undef PHASE
#undef AFRD
#undef BFRD
#undef ISSUE

    // epilogue: C/D layout col = lane&15, row = (lane>>4)*4 + reg (m89-verified)
    float* dst = out + (size_t)bz * ((size_t)B_DIM * O_DIM);
#pragma unroll
    for (int mt = 0; mt < 8; ++mt)
#pragma unroll
        for (int nt = 0; nt < 4; ++nt) {
            int rw = m0 + wm * 128 + mt * 16 + q * 4;
            int cc = n0 + wn * 64 + nt * 16 + fr;
#pragma unroll
            for (int rg = 0; rg < 4; ++rg)
                dst[(size_t)(rw + rg) * O_DIM + cc] = acc[mt][nt][rg];
        }
}

// ---------------------------------------------------------------------------
// Sum the KSPLIT partial buffers into out. 71 MB traffic, BW-bound.
__global__ __launch_bounds__(256) void reduce16(const float* __restrict__ parts,
                                                float* __restrict__ out) {
    constexpr int N4 = B_DIM * O_DIM / 4;
    int i = blockIdx.x * 256 + threadIdx.x;       // float4 index
    const float4* p = (const float4*)parts;
    float4 a = p[i];
#pragma unroll
    for (int z = 1; z < KSPLIT; ++z) {
        float4 b = p[(size_t)z * N4 + i];
        a.x += b.x; a.y += b.y; a.z += b.z; a.w += b.w;
    }
    ((float4*)out)[i] = a;
}

// ---------------------------------------------------------------------------
// Zero-workspace fallback (only if ws_size too small): correct but slow.
__global__ __launch_bounds__(256) void kan_fallback(const float* __restrict__ x,
                                                    const float* __restrict__ pw,
                                                    const float* __restrict__ bw,
                                                    const float* __restrict__ sw,
                                                    const float* __restrict__ sc,
                                                    float* __restrict__ out) {
    __shared__ float s_neg[J_DIM], s_pos[J_DIM], s_bas[J_DIM][5];
    __shared__ int s_k0[J_DIM];
    int b = blockIdx.x;
    int t = threadIdx.x;
#pragma unroll
    for (int jj = 0; jj < 2; ++jj) {
        int j = t + jj * 256;
        float xv = x[(size_t)b * J_DIM + j];
        float xc = fminf(fmaxf(xv, -1.f), 1.f);
        float pos = fmaxf(xc, 0.f);
        s_pos[j] = pos;
        s_neg[j] = xc - pos;
        int k0; float Nv[5];
        bspline5(xc, k0, Nv);
        s_k0[j] = k0;
#pragma unroll
        for (int r = 0; r < 5; ++r) s_bas[j][r] = Nv[r];
    }
    __syncthreads();
    for (int i = t; i < O_DIM; i += 256) {
        float acc = 0.f;
        for (int j = 0; j < J_DIM; ++j) {
            size_t ij = (size_t)i * J_DIM + j;
            float bwv = bw[ij];
            acc += bwv * (pw[ij] * s_neg[j] + s_pos[j]);
            int k0 = s_k0[j];
            const float* cp = sc + ij * 20;
            float sp = 0.f;
#pragma unroll
            for (int r = 0; r < 5; ++r) {
                int k = k0 + r;
                if (k >= 0) sp += s_bas[j][r] * cp[k];
            }
            acc += sw[ij] * sp;
        }
        out[(size_t)b * O_DIM + i] = acc;
    }
}

// ---------------------------------------------------------------------------
extern "C" void kernel_launch(void* const* d_in, const int* in_sizes, int n_in,
                              void* d_out, int out_size, void* d_ws, size_t ws_size,
                              hipStream_t stream) {
    const float* x  = (const float*)d_in[0];
    const float* pw = (const float*)d_in[1];
    const float* bw = (const float*)d_in[2];
    const float* sw = (const float*)d_in[3];
    const float* sc = (const float*)d_in[4];
    float* out = (float*)d_out;

    const size_t abct = (size_t)(B_DIM + O_DIM) * K_TOT * sizeof(half_t);       // 57.7 MB
    const size_t parts_bytes = (size_t)KSPLIT * B_DIM * O_DIM * sizeof(float);  // 67.1 MB

    if (ws_size >= abct + parts_bytes) {
        half_t* A  = (half_t*)d_ws;
        half_t* Ct = A + (size_t)B_DIM * K_TOT;
        float* parts = (float*)((char*)d_ws + abct);   // 16B-aligned (abct % 16 == 0)

        prep2<<<256 + B_DIM / 2, 256, 0, stream>>>(x, pw, bw, sw, sc, A, Ct);
        dim3 g(B_DIM / BM, O_DIM / BN, KSPLIT);        // (8, 2, 16)
        gemm16_f16<<<g, 512, 0, stream>>>(A, Ct, parts);
        reduce16<<<(B_DIM * O_DIM / 4) / 256, 256, 0, stream>>>(parts, out);
    } else {
        kan_fallback<<<B_DIM, 256, 0, stream>>>(x, pw, bw, sw, sc, out);
    }
}

// Round 6
// 129.233 us; speedup vs baseline: 1.0613x; 1.0613x over previous
//
#include <hip/hip_runtime.h>

// KAN layer as one fused fp16 MFMA GEMM:
//   out[b,i] = sum_j [ neg*bw*pw + pos*bw + sum_k basis[b,j,k]*sw[i,j]*sc[i,j,k] ]
// A  [2048 x 11264] fp16 : per j, 22 slots = {20 basis (5 nonzero), neg, pos}
// Ct [ 512 x 11264] fp16 : per j, 22 slots = {sw*sc[0..19], bw*pw, bw}   (B^T layout)
// R9b: RESUBMIT of R9 (previous bench was an infra failure — container
//     acquisition died twice; no measurement was taken). Strict A/B round:
//     ONE change vs R6 (127.4 us): prep_all -> prep2 (register-built records,
//     4-j granularity; predicted 37 -> ~15 us). gemm is R6's proven 2-phase
//     BK=32 KSPLIT=8 kernel (~40 us, conflicts=0, counters known from R5)
//     + reduce8. This decodes prep2's true cost from total arithmetic, and
//     retroactively decodes R8's gemm16 (137.2 = 41 + prep2 + gemm16 + 11 + gaps).
// R6: XCD pin z = lid%8 (neutral, kept). R5: non-atomic partials + reduce8;
//     3-deep LDS pipeline, counted vmcnt(4) + raw s_barrier, setprio on MFMA.
// ws usage: A = 46.1 MB, Ct = 11.5 MB, partials = 33.6 MB (91.2 MB total).

typedef _Float16 half_t;
typedef __attribute__((ext_vector_type(8))) _Float16 half8;
typedef __attribute__((ext_vector_type(4))) float floatx4;

#define B_DIM   2048
#define J_DIM   512
#define O_DIM   512
#define SLOTS   22
#define K_TOT   (J_DIM * SLOTS)      // 11264
#define MTILE   128
#define NTILE   128
#define BK      32
#define KSPLIT  8                    // == NXCD, one z per XCD

// ---------------------------------------------------------------------------
// Quartic B-spline local basis, uniform knots g_i = -1.5 + i*(3.125/24).
// (Reference quirk: linspace(-1.5, 1.625, 25) -> spacing 3.125/24, NOT 0.125.)
// m in [3,19]; window k = m-4 .. m, entries with k<0 dropped.
__device__ __forceinline__ void bspline5(float xc, int& k0, float Nv[5]) {
    const float invS = 7.68f;              // 24/3.125 (exact ratio)
    float u = (xc + 1.5f) * invS;          // knot units
    int m = (int)u;
    m = min(max(m, 3), 19);
    k0 = m - 4;
    Nv[0] = 1.f; Nv[1] = 0.f; Nv[2] = 0.f; Nv[3] = 0.f; Nv[4] = 0.f;
#pragma unroll
    for (int d = 1; d <= 4; ++d) {
        float nw[5];
        float inv_d = 1.0f / (float)d;
#pragma unroll
        for (int r = 0; r < 5; ++r) {
            if (r > d) { nw[r] = 0.f; continue; }
            float kk = (float)(m - d + r);
            float acc = 0.f;
            if (r >= 1) acc += (u - kk) * Nv[r - 1];
            if (r < d)  acc += (kk + (float)(d + 1) - u) * Nv[r];
            nw[r] = acc * inv_d;
        }
#pragma unroll
        for (int r = 0; r < 5; ++r) Nv[r] = nw[r];
    }
}

__device__ __forceinline__ unsigned packh2(float a, float b) {
    half_t ha = (half_t)a, hb = (half_t)b;    // RTN, identical to old path
    unsigned short ua = __builtin_bit_cast(unsigned short, ha);
    unsigned short ub = __builtin_bit_cast(unsigned short, hb);
    return (unsigned)ua | ((unsigned)ub << 16);
}

// ---------------------------------------------------------------------------
// prep2: blocks [0,256) build Ct (2 i-rows each, register-only);
//        blocks [256,1280) build A (2 b-rows each, private-LDS scatter).
// Thread: sub = t>>7 selects the row within the block; jq = t&127 -> j0=4*jq.
__global__ __launch_bounds__(256) void prep2(const float* __restrict__ x,
                                             const float* __restrict__ pw,
                                             const float* __restrict__ bw,
                                             const float* __restrict__ sw,
                                             const float* __restrict__ sc,
                                             half_t* __restrict__ A,
                                             half_t* __restrict__ Ct) {
    __shared__ half_t sbuf[2][128 * 88];   // 45056 B, prep_A path only
    int bid = blockIdx.x;
    int t = threadIdx.x;
    int sub = t >> 7;          // 0/1: which row of the block's pair
    int jq  = t & 127;         // j-quad index
    int j0  = jq * 4;

    if (bid < 256) {
        // ---- prep_C: 4 records built fully in registers, no LDS.
        int i = bid * 2 + sub;
        size_t ij0 = (size_t)i * J_DIM + j0;
        float4 s4 = *(const float4*)(sw + ij0);
        float4 b4 = *(const float4*)(bw + ij0);
        float4 p4 = *(const float4*)(pw + ij0);
        const float4* sp4 = (const float4*)(sc + ij0 * 20);  // 20 float4s
        unsigned u[44];
#pragma unroll
        for (int jj = 0; jj < 4; ++jj) {
            float s = ((const float*)&s4)[jj];
            float b = ((const float*)&b4)[jj];
            float p = ((const float*)&p4)[jj];
#pragma unroll
            for (int v = 0; v < 5; ++v) {                   // 20 coeffs
                float4 c4 = sp4[jj * 5 + v];
                u[jj * 11 + v * 2 + 0] = packh2(s * c4.x, s * c4.y);
                u[jj * 11 + v * 2 + 1] = packh2(s * c4.z, s * c4.w);
            }
            u[jj * 11 + 10] = packh2(b * p, b);             // slots 20,21
        }
        uint4* dst = (uint4*)(Ct + (size_t)i * K_TOT + (size_t)j0 * SLOTS);
#pragma unroll
        for (int v = 0; v < 11; ++v)
            dst[v] = make_uint4(u[4 * v], u[4 * v + 1], u[4 * v + 2], u[4 * v + 3]);
        return;
    }

    // ---- prep_A: 4 records via private-LDS scatter (no cross-thread deps
    // until the single pre-copy barrier).
    int b0 = (bid - 256) * 2;
    int b = b0 + sub;
    float4 x4 = *(const float4*)(x + (size_t)b * J_DIM + j0);
    half_t* reg = &sbuf[sub][jq * 88];      // 176 B, 16B-aligned, stride 11 quads

    // zero 88 halfs with 11 conflict-free b128 writes (stride 176 B = 11 quads)
    half8 z;
#pragma unroll
    for (int e = 0; e < 8; ++e) z[e] = (half_t)0.f;
#pragma unroll
    for (int v = 0; v < 11; ++v) *(half8*)(reg + v * 8) = z;

#pragma unroll
    for (int jj = 0; jj < 4; ++jj) {
        float xv = ((const float*)&x4)[jj];
        float xc = fminf(fmaxf(xv, -1.f), 1.f);
        float pos = fmaxf(xc, 0.f);
        float neg = xc - pos;
        int k0; float Nv[5];
        bspline5(xc, k0, Nv);
        half_t* rb = reg + jj * SLOTS;
#pragma unroll
        for (int rr = 0; rr < 5; ++rr) {
            int k = k0 + rr;
            if (k >= 0) rb[k] = (half_t)Nv[rr];   // k <= 19 guaranteed
        }
        *(unsigned*)(rb + 20) = packh2(neg, pos); // 4B-aligned (44*jj+40)
    }
    __syncthreads();

    // coalesced cooperative store of the 2 complete rows (45056 B)
    const uint4* src = (const uint4*)&sbuf[0][0];
    uint4* dst = (uint4*)(A + (size_t)b0 * K_TOT);
#pragma unroll
    for (int v = 0; v < 11; ++v) dst[v * 256 + t] = src[v * 256 + t];
}

// ---------------------------------------------------------------------------
// GEMM (R6-proven): Grid (16, 4, 8), 256 thr. 3-deep LDS pipeline:
//   prologue issues chunks 0,1; iter c waits vmcnt(4) (chunk c's 4 loads done,
//   chunk c+1's still flying), raw s_barrier, issues chunk c+2, then
//   ds_read + 16 MFMA under setprio(1). vmcnt never drains to 0 in the loop.
// XOR swizzle on the global source k-quad kills fragment-read conflicts
// (R3/R5 measured: SQ_LDS_BANK_CONFLICT = 0).
// XCD pin: z = lid%8 — each XCD owns one k-split's operand slices.
__global__ __launch_bounds__(256, 3) void gemm_f16(const half_t* __restrict__ A,
                                                   const half_t* __restrict__ Bt,
                                                   float* __restrict__ out) {
    constexpr int KS_LEN = K_TOT / KSPLIT;     // 1408
    constexpr int KCH = KS_LEN / BK;           // 44

    __shared__ half_t As[3][MTILE * BK];   // 3 x 8 KB
    __shared__ half_t Bs[3][NTILE * BK];   // 3 x 8 KB   (48 KB total)

    // dispatch order is x-fastest: lid = x + 16*(y + 4*z); XCD = lid % 8.
    int lid = blockIdx.x + (B_DIM / MTILE) * (blockIdx.y + (O_DIM / NTILE) * blockIdx.z);
    int bz = lid & 7;                    // one k-split per XCD
    int rem = lid >> 3;                  // 0..63 within the XCD
    int bx = rem & (B_DIM / MTILE - 1);  // 16 m-blocks
    int by = rem >> 4;                   // 4 n-blocks

    int m0 = bx * MTILE;
    int n0 = by * NTILE;
    int ks = bz * KS_LEN;       // halfs; 16B-aligned

    int t = threadIdx.x;
    int w = t >> 6;          // wave 0..3
    int l = t & 63;
    int wm = w >> 1, wn = w & 1;

    floatx4 acc[4][4] = {};

    int lrow = l >> 2;                            // 0..15: row within 16-row chunk
    int lkof = (((l & 3) ^ ((l >> 3) & 3)) * 8);  // swizzled k-quad source offset

    const half_t* gA = A + (size_t)m0 * K_TOT + ks;
    const half_t* gB = Bt + (size_t)n0 * K_TOT + ks;

    int q = l >> 4;               // 0..3
    int fr = l & 15;              // 0..15
    int qs = (q ^ ((fr >> 1) & 3)) * 8;  // swizzled read offset (elements)

// 4 global_load_lds per thread per chunk (2 A + 2 B) -> vmcnt counts in 4s.
#define ISSUE_LOADS(c, p)                                                     \
    {                                                                         \
        int kb = (c) * BK;                                                    \
        _Pragma("unroll")                                                     \
        for (int n = 0; n < 2; ++n) {                                         \
            int r = (w * 2 + n) * 16 + lrow;                                  \
            __builtin_amdgcn_global_load_lds(                                 \
                (const __attribute__((address_space(1))) unsigned int*)       \
                    (gA + (size_t)r * K_TOT + kb + lkof),                     \
                (__attribute__((address_space(3))) unsigned int*)             \
                    (&As[p][0] + (w * 2 + n) * 512),                          \
                16, 0, 0);                                                    \
            __builtin_amdgcn_global_load_lds(                                 \
                (const __attribute__((address_space(1))) unsigned int*)       \
                    (gB + (size_t)r * K_TOT + kb + lkof),                     \
                (__attribute__((address_space(3))) unsigned int*)             \
                    (&Bs[p][0] + (w * 2 + n) * 512),                          \
                16, 0, 0);                                                    \
        }                                                                     \
    }

    ISSUE_LOADS(0, 0)
    ISSUE_LOADS(1, 1)

    int pb = 0;                              // consume buffer = c % 3
    for (int c = 0; c < KCH; ++c) {
        if (c + 2 < KCH) {
            // 8 outstanding (c, c+1); keep c+1's 4 flying across the barrier.
            asm volatile("s_waitcnt vmcnt(4)" ::: "memory");
            __builtin_amdgcn_s_barrier();
            int pn = pb + 2; if (pn >= 3) pn -= 3;
            ISSUE_LOADS(c + 2, pn)
        } else if (c + 2 == KCH) {
            asm volatile("s_waitcnt vmcnt(4)" ::: "memory");
            __builtin_amdgcn_s_barrier();
        } else {
            asm volatile("s_waitcnt vmcnt(0)" ::: "memory");
            __builtin_amdgcn_s_barrier();
        }

        half8 af[4], bf[4];
#pragma unroll
        for (int mt = 0; mt < 4; ++mt)
            af[mt] = *(const half8*)(&As[pb][0] + (wm * 64 + mt * 16 + fr) * BK + qs);
#pragma unroll
        for (int nt = 0; nt < 4; ++nt)
            bf[nt] = *(const half8*)(&Bs[pb][0] + (wn * 64 + nt * 16 + fr) * BK + qs);

        __builtin_amdgcn_s_setprio(1);
#pragma unroll
        for (int mt = 0; mt < 4; ++mt)
#pragma unroll
            for (int nt = 0; nt < 4; ++nt)
                acc[mt][nt] = __builtin_amdgcn_mfma_f32_16x16x32_f16(
                    af[mt], bf[nt], acc[mt][nt], 0, 0, 0);
        __builtin_amdgcn_s_setprio(0);

        if (++pb == 3) pb = 0;
    }
#undef ISSUE_LOADS

    // epilogue: C/D layout col = lane&15, row = (lane>>4)*4 + reg (m89-verified)
    float* dst = out + (size_t)bz * ((size_t)B_DIM * O_DIM);
#pragma unroll
    for (int mt = 0; mt < 4; ++mt)
#pragma unroll
        for (int nt = 0; nt < 4; ++nt) {
            int rr = m0 + wm * 64 + mt * 16 + q * 4;
            int cc = n0 + wn * 64 + nt * 16 + fr;
#pragma unroll
            for (int r = 0; r < 4; ++r)
                dst[(size_t)(rr + r) * O_DIM + cc] = acc[mt][nt][r];
        }
}

// ---------------------------------------------------------------------------
// Sum the KSPLIT partial buffers into out. 37.7 MB traffic, BW-bound.
__global__ __launch_bounds__(256) void reduce8(const float* __restrict__ parts,
                                               float* __restrict__ out) {
    constexpr int N4 = B_DIM * O_DIM / 4;
    int i = blockIdx.x * 256 + threadIdx.x;       // float4 index
    const float4* p = (const float4*)parts;
    float4 a = p[i];
#pragma unroll
    for (int z = 1; z < KSPLIT; ++z) {
        float4 b = p[(size_t)z * N4 + i];
        a.x += b.x; a.y += b.y; a.z += b.z; a.w += b.w;
    }
    ((float4*)out)[i] = a;
}

// ---------------------------------------------------------------------------
// Zero-workspace fallback (only if ws_size too small): correct but slow.
__global__ __launch_bounds__(256) void kan_fallback(const float* __restrict__ x,
                                                    const float* __restrict__ pw,
                                                    const float* __restrict__ bw,
                                                    const float* __restrict__ sw,
                                                    const float* __restrict__ sc,
                                                    float* __restrict__ out) {
    __shared__ float s_neg[J_DIM], s_pos[J_DIM], s_bas[J_DIM][5];
    __shared__ int s_k0[J_DIM];
    int b = blockIdx.x;
    int t = threadIdx.x;
#pragma unroll
    for (int jj = 0; jj < 2; ++jj) {
        int j = t + jj * 256;
        float xv = x[(size_t)b * J_DIM + j];
        float xc = fminf(fmaxf(xv, -1.f), 1.f);
        float pos = fmaxf(xc, 0.f);
        s_pos[j] = pos;
        s_neg[j] = xc - pos;
        int k0; float Nv[5];
        bspline5(xc, k0, Nv);
        s_k0[j] = k0;
#pragma unroll
        for (int r = 0; r < 5; ++r) s_bas[j][r] = Nv[r];
    }
    __syncthreads();
    for (int i = t; i < O_DIM; i += 256) {
        float acc = 0.f;
        for (int j = 0; j < J_DIM; ++j) {
            size_t ij = (size_t)i * J_DIM + j;
            float bwv = bw[ij];
            acc += bwv * (pw[ij] * s_neg[j] + s_pos[j]);
            int k0 = s_k0[j];
            const float* cp = sc + ij * 20;
            float sp = 0.f;
#pragma unroll
            for (int r = 0; r < 5; ++r) {
                int k = k0 + r;
                if (k >= 0) sp += s_bas[j][r] * cp[k];
            }
            acc += sw[ij] * sp;
        }
        out[(size_t)b * O_DIM + i] = acc;
    }
}

// ---------------------------------------------------------------------------
extern "C" void kernel_launch(void* const* d_in, const int* in_sizes, int n_in,
                              void* d_out, int out_size, void* d_ws, size_t ws_size,
                              hipStream_t stream) {
    const float* x  = (const float*)d_in[0];
    const float* pw = (const float*)d_in[1];
    const float* bw = (const float*)d_in[2];
    const float* sw = (const float*)d_in[3];
    const float* sc = (const float*)d_in[4];
    float* out = (float*)d_out;

    const size_t abct = (size_t)(B_DIM + O_DIM) * K_TOT * sizeof(half_t);       // 57.7 MB
    const size_t parts_bytes = (size_t)KSPLIT * B_DIM * O_DIM * sizeof(float);  // 33.6 MB

    if (ws_size >= abct + parts_bytes) {
        half_t* A  = (half_t*)d_ws;
        half_t* Ct = A + (size_t)B_DIM * K_TOT;
        float* parts = (float*)((char*)d_ws + abct);   // 16B-aligned (abct % 16 == 0)

        prep2<<<256 + B_DIM / 2, 256, 0, stream>>>(x, pw, bw, sw, sc, A, Ct);
        dim3 g(B_DIM / MTILE, O_DIM / NTILE, KSPLIT);  // (16, 4, 8)
        gemm_f16<<<g, 256, 0, stream>>>(A, Ct, parts);
        reduce8<<<(B_DIM * O_DIM / 4) / 256, 256, 0, stream>>>(parts, out);
    } else {
        kan_fallback<<<B_DIM, 256, 0, stream>>>(x, pw, bw, sw, sc, out);
    }
}